// Round 2
// baseline (1489.274 us; speedup 1.0000x reference)
//
#include <hip/hip_runtime.h>
#include <hip/hip_bf16.h>

// MoRE: B=32768 rows, E=16 experts, M=64 slots, D=256 dims, all fp32.
// Outputs (concat, float): winners[B], max_scores[B], y[B,E,D], g[B,E], attn[B,E,M]
//
// Kernel 1: grid (B/64, E), block 512 (8 waves x 8 rows/wave), one expert per block.
//   Phase 1: logits via LDS-staged K (two d-halves, padded stride 132 -> bank-clean
//            b128 reads with lane=m). x rows read via wave-uniform scalar loads.
//   Softmax: in-wave shfl_xor butterflies (lane holds one m).
//   Phase 2: y = attn @ V via LDS-staged V (two m-halves, lane=d chunk of 4).
//   Epilogue: fused gate/cos/norm reductions; f = g*cos -> workspace.
// Kernel 2: per-row first-max-wins argmax over 16 f values -> winners (as float) + scores.

__device__ __forceinline__ void fma4(float a, const float4& v, float4& acc) {
    acc.x = fmaf(a, v.x, acc.x);
    acc.y = fmaf(a, v.y, acc.y);
    acc.z = fmaf(a, v.z, acc.z);
    acc.w = fmaf(a, v.w, acc.w);
}

__global__ __launch_bounds__(512, 4) void more_main(
    const float* __restrict__ x, const float* __restrict__ Kp,
    const float* __restrict__ Vp, const float* __restrict__ wgp,
    const float* __restrict__ bgp, float* __restrict__ out_y,
    float* __restrict__ out_g, float* __restrict__ out_attn,
    float* __restrict__ f_ws)
{
    constexpr int E = 16, M = 64, D = 256;
    constexpr int KSTR = 132;  // 128 + 4 pad: lane groups of 8 cover all 32 banks on b128

    __shared__ __align__(16) float sKV[64 * KSTR];    // 33,792 B (reused for V: 32*256 floats)
    __shared__ __align__(16) float sAttn[8][8][64];   // 16,384 B

    const int tid  = threadIdx.x;
    const int wave = __builtin_amdgcn_readfirstlane(tid >> 6);  // force wave-uniform
    const int lane = tid & 63;
    const int e    = blockIdx.y;
    const int myRow0 = blockIdx.x * 64 + wave * 8;

    const float* Ke = Kp + (size_t)e * M * D;
    const float* Ve = Vp + (size_t)e * M * D;

    // ---------------- Phase 1: logits[r][m] (lane = m) ----------------
    float acc[8];
#pragma unroll
    for (int r = 0; r < 8; ++r) acc[r] = 0.f;

#pragma unroll
    for (int h = 0; h < 2; ++h) {
        // stage K[:, h*128 .. h*128+127] into sKV (padded stride)
#pragma unroll
        for (int j = 0; j < 4; ++j) {
            int i = tid + j * 512;          // float4 index, 2048 total
            int flat = i * 4;
            int m  = flat >> 7;
            int dd = flat & 127;
            float4 v = *(const float4*)(Ke + m * D + h * 128 + dd);
            *(float4*)&sKV[m * KSTR + dd] = v;
        }
        __syncthreads();

#pragma unroll 4
        for (int d = 0; d < 128; d += 4) {
            float4 k4 = *(const float4*)&sKV[lane * KSTR + d];
#pragma unroll
            for (int r = 0; r < 8; ++r) {
                const float4 xv = *(const float4*)(x + (size_t)(myRow0 + r) * D + h * 128 + d);
                acc[r] = fmaf(k4.x, xv.x, acc[r]);
                acc[r] = fmaf(k4.y, xv.y, acc[r]);
                acc[r] = fmaf(k4.z, xv.z, acc[r]);
                acc[r] = fmaf(k4.w, xv.w, acc[r]);
            }
        }
        __syncthreads();  // protect sKV before restage / V stage
    }

    // ---------------- Softmax per row (in-wave, lane = m) ----------------
#pragma unroll
    for (int r = 0; r < 8; ++r) {
        float lg = acc[r] * 0.0625f;  // / sqrt(256)
        float mx = lg;
#pragma unroll
        for (int off = 32; off; off >>= 1) mx = fmaxf(mx, __shfl_xor(mx, off, 64));
        float p = expf(lg - mx);
        float s = p;
#pragma unroll
        for (int off = 32; off; off >>= 1) s += __shfl_xor(s, off, 64);
        float a = p / s;
        sAttn[wave][r][lane] = a;  // same-wave producer/consumer: no barrier needed
        out_attn[((size_t)(myRow0 + r) * E + e) * M + lane] = a;
    }

    // ---------------- Phase 2: y[r][d0..d0+3] = sum_m attn*V (lane = d/4) ----------------
    const int d0 = lane * 4;
    float4 yacc[8];
#pragma unroll
    for (int r = 0; r < 8; ++r) yacc[r] = make_float4(0.f, 0.f, 0.f, 0.f);

#pragma unroll
    for (int h = 0; h < 2; ++h) {
        // stage V rows [h*32 .. h*32+31] into sKV (stride 256, no pad needed: lane-contiguous)
#pragma unroll
        for (int j = 0; j < 4; ++j) {
            int i = tid + j * 512;
            int flat = i * 4;
            int mm = flat >> 8;
            int dd = flat & 255;
            float4 v = *(const float4*)(Ve + (size_t)(h * 32 + mm) * D + dd);
            *(float4*)&sKV[mm * 256 + dd] = v;
        }
        __syncthreads();

#pragma unroll
        for (int mc = 0; mc < 32; mc += 8) {
            float4 vv[8];
#pragma unroll
            for (int j = 0; j < 8; ++j) vv[j] = *(const float4*)&sKV[(mc + j) * 256 + d0];
#pragma unroll
            for (int r = 0; r < 8; ++r) {
                const float* ar = &sAttn[wave][r][h * 32 + mc];
                float4 A0 = *(const float4*)(ar);
                float4 A1 = *(const float4*)(ar + 4);
                fma4(A0.x, vv[0], yacc[r]);
                fma4(A0.y, vv[1], yacc[r]);
                fma4(A0.z, vv[2], yacc[r]);
                fma4(A0.w, vv[3], yacc[r]);
                fma4(A1.x, vv[4], yacc[r]);
                fma4(A1.y, vv[5], yacc[r]);
                fma4(A1.z, vv[6], yacc[r]);
                fma4(A1.w, vv[7], yacc[r]);
            }
        }
        __syncthreads();  // protect sKV before restage
    }

    // ---------------- Epilogue: gate, cos, f; write y ----------------
    const float4 wgv = *(const float4*)(wgp + (size_t)e * D + d0);
    const float bge = bgp[e];
#pragma unroll
    for (int r = 0; r < 8; ++r) {
        const size_t row = (size_t)(myRow0 + r);
        const float4 xv = *(const float4*)(x + row * D + d0);
        float xy = xv.x * yacc[r].x + xv.y * yacc[r].y + xv.z * yacc[r].z + xv.w * yacc[r].w;
        float yy = yacc[r].x * yacc[r].x + yacc[r].y * yacc[r].y + yacc[r].z * yacc[r].z + yacc[r].w * yacc[r].w;
        float xx = xv.x * xv.x + xv.y * xv.y + xv.z * xv.z + xv.w * xv.w;
        float xw = xv.x * wgv.x + xv.y * wgv.y + xv.z * wgv.z + xv.w * wgv.w;
#pragma unroll
        for (int off = 32; off; off >>= 1) {
            xy += __shfl_xor(xy, off, 64);
            yy += __shfl_xor(yy, off, 64);
            xx += __shfl_xor(xx, off, 64);
            xw += __shfl_xor(xw, off, 64);
        }
        *(float4*)&out_y[(row * E + e) * D + d0] = yacc[r];
        if (lane == 0) {
            float gv = 1.f / (1.f + expf(-(xw + bge)));
            float cosv = xy / (sqrtf(xx) * sqrtf(yy) + 1e-8f);
            out_g[row * E + e] = gv;
            f_ws[row * E + e] = gv * cosv;
        }
    }
}

__global__ __launch_bounds__(256) void more_winner(
    const float* __restrict__ f, float* __restrict__ out_w,
    float* __restrict__ out_s, int B)
{
    int t = blockIdx.x * blockDim.x + threadIdx.x;
    if (t >= B) return;
    const float* fr = f + (size_t)t * 16;
    float best = fr[0];
    int be = 0;
#pragma unroll
    for (int e2 = 1; e2 < 16; ++e2) {
        float v = fr[e2];
        if (v > best) { best = v; be = e2; }  // strict > keeps first max (jnp.argmax)
    }
    out_w[t] = (float)be;
    out_s[t] = best;
}

extern "C" void kernel_launch(void* const* d_in, const int* in_sizes, int n_in,
                              void* d_out, int out_size, void* d_ws, size_t ws_size,
                              hipStream_t stream)
{
    const float* x   = (const float*)d_in[0];
    const float* Kp  = (const float*)d_in[1];
    const float* Vp  = (const float*)d_in[2];
    const float* wgp = (const float*)d_in[3];
    const float* bgp = (const float*)d_in[4];

    const int B = 32768, E = 16, M = 64, D = 256;

    float* out   = (float*)d_out;
    float* out_w = out;                       // winners [B] (as float)
    float* out_s = out + B;                   // max_scores [B]
    float* out_y = out + 2 * (size_t)B;       // y [B,E,D]
    float* out_g = out_y + (size_t)B * E * D; // g [B,E]
    float* out_a = out_g + (size_t)B * E;     // attn [B,E,M]

    float* f_ws = (float*)d_ws;               // f scores [B,E] (2 MB)

    dim3 g1(B / 64, E), b1(512);
    more_main<<<g1, b1, 0, stream>>>(x, Kp, Vp, wgp, bgp, out_y, out_g, out_a, f_ws);
    more_winner<<<(B + 255) / 256, 256, 0, stream>>>(f_ws, out_w, out_s, B);
}